// Round 5
// baseline (803.336 us; speedup 1.0000x reference)
//
#include <hip/hip_runtime.h>

#define DIN 2048
#define NH 16
#define DH 128
#define SEQ 2048
#define BB 2
#define N3 6144
#define MM 4096  // BB*SEQ

typedef __bf16 bf16;
typedef __attribute__((ext_vector_type(8))) __bf16 bf16x8;
typedef __attribute__((ext_vector_type(4))) __bf16 bf16x4;
typedef __attribute__((ext_vector_type(2))) __bf16 bf16x2;
typedef __attribute__((ext_vector_type(4))) float f32x4;

__device__ __forceinline__ f32x4 mfma16(bf16x8 a, bf16x8 b, f32x4 c) {
  return __builtin_amdgcn_mfma_f32_16x16x32_bf16(a, b, c, 0, 0, 0);
}

__device__ __forceinline__ void async16(const void* g, void* l) {
  __builtin_amdgcn_global_load_lds((const __attribute__((address_space(1))) void*)g,
                                   (__attribute__((address_space(3))) void*)l, 16, 0, 0);
}

// ---------------- dtype sniff ----------------
__global__ void sniff_k(const unsigned short* __restrict__ x, int* __restrict__ flag) {
  __shared__ int cnt;
  if (threadIdx.x == 0) cnt = 0;
  __syncthreads();
  unsigned short u = x[threadIdx.x * 2];
  int e = (u >> 7) & 0xff;
  if (e >= 108 && e <= 140) atomicAdd(&cnt, 1);
  __syncthreads();
  if (threadIdx.x == 0) *flag = (cnt >= 128) ? 1 : 0;
}

// ---------------- casts ----------------
__global__ __launch_bounds__(256) void cast_x_k(const void* __restrict__ in, bf16* __restrict__ out,
                                                const int* __restrict__ flag) {
  size_t i = ((size_t)blockIdx.x * 256 + threadIdx.x) * 8;
  if (*flag) {
    *(bf16x8*)(out + i) = *(const bf16x8*)((const bf16*)in + i);
  } else {
    const float* f = (const float*)in;
    bf16x8 v;
    for (int j = 0; j < 8; j++) v[j] = (bf16)f[i + j];
    *(bf16x8*)(out + i) = v;
  }
}

// 32x32 transpose tile; write phase emits 4B bf16x2 pairs (2x wider than scalar).
__global__ __launch_bounds__(256) void cast_wT_k(const void* __restrict__ in, bf16* __restrict__ out,
                                                 const int* __restrict__ flag, int R, int C) {
  __shared__ float t[32][33];
  int c0 = blockIdx.x * 32, r0 = blockIdx.y * 32;
  int tx = threadIdx.x & 31, ty = threadIdx.x >> 5;
  bool isb = *flag != 0;
  for (int j = 0; j < 4; j++) {
    int r = ty + j * 8;
    size_t idx = (size_t)(r0 + r) * C + c0 + tx;
    float v = isb ? (float)((const bf16*)in)[idx] : ((const float*)in)[idx];
    t[r][tx] = v;
  }
  __syncthreads();
  int tx8 = threadIdx.x & 15;  // row-pair index: rows 2*tx8, 2*tx8+1
  int cy = threadIdx.x >> 4;   // 0..15
  for (int j = 0; j < 2; j++) {
    int c = cy + j * 16;
    bf16x2 v;
    v[0] = (bf16)t[2 * tx8][c];
    v[1] = (bf16)t[2 * tx8 + 1][c];
    *(bf16x2*)&out[(size_t)(c0 + c) * R + r0 + 2 * tx8] = v;
  }
}

// ---------------- qkv GEMM (proven 128x128, BK=64, xor-swizzled chunks) ----
// Launched as TWO M-half dispatches (each grid 48x16 = 768 blocks = exactly
// 3.0 rounds; zero tail) -- drops the rocprof top-5 floor to ~60 us so the
// next-largest kernel becomes visible. Epilogue fuses:
//  * V transpose+swizzle direct write (B,H,DH,S), bf16x4 stores
//  * RoPE for Q/K on fp32 acc (pair partner = lane l15^1 via shfl_xor;
//    `part` is block-uniform so the shfl is in uniform control flow);
//    Q gets DH^-0.5 * log2(e) folded in (scores in log2 domain);
//    K rows carry the 16B-chunk xor swizzle consumed by attn's DMA staging.
__global__ __launch_bounds__(256) void gemm_qkv_k(const bf16* __restrict__ A, const bf16* __restrict__ BT,
                                                  bf16* __restrict__ Qb, bf16* __restrict__ Kb,
                                                  bf16* __restrict__ Vt, int m0base) {
  __shared__ __align__(16) bf16 As[128 * 64];
  __shared__ __align__(16) bf16 Bs[128 * 64];
  const int K = DIN;
  int m0 = m0base + blockIdx.y * 128, n0 = blockIdx.x * 128;
  int tid = threadIdx.x, w = tid >> 6, l = tid & 63;
  int l15 = l & 15, quad = l >> 4;
  int wm = (w & 1) * 64, wn = (w >> 1) * 64;
  f32x4 zero = {0.f, 0.f, 0.f, 0.f};
  f32x4 acc[4][4];
  for (int i = 0; i < 4; i++)
    for (int j = 0; j < 4; j++) acc[i][j] = zero;
  int gch = (l & 7) ^ (l >> 3);  // swizzled source chunk for this lane
  const bf16* Ag = A + (size_t)(m0 + w * 32 + (l >> 3)) * K + gch * 8;
  const bf16* Bg = BT + (size_t)(n0 + w * 32 + (l >> 3)) * K + gch * 8;
  bf16* AsW = As + w * 2048;  // wave stages rows w*32..+31 (4 KB)
  bf16* BsW = Bs + w * 2048;
  for (int k0 = 0; k0 < K; k0 += 64) {
    __syncthreads();
    for (int j = 0; j < 4; j++) async16(Ag + k0 + (size_t)j * 8 * K, AsW + j * 512);
    for (int j = 0; j < 4; j++) async16(Bg + k0 + (size_t)j * 8 * K, BsW + j * 512);
    __syncthreads();
    for (int kk = 0; kk < 2; kk++) {
      bf16x8 af[4], bfv[4];
      for (int i = 0; i < 4; i++)
        af[i] = *(const bf16x8*)&As[(wm + i * 16 + l15) * 64 + (((kk * 4 + quad) ^ (l15 & 7)) << 3)];
      for (int j = 0; j < 4; j++)
        bfv[j] = *(const bf16x8*)&Bs[(wn + j * 16 + l15) * 64 + (((kk * 4 + quad) ^ (l15 & 7)) << 3)];
      for (int i = 0; i < 4; i++)
        for (int j = 0; j < 4; j++) acc[i][j] = mfma16(af[i], bfv[j], acc[i][j]);
    }
  }
  for (int j = 0; j < 4; j++) {
    int col = n0 + wn + j * 16 + l15;
    int part = col >> 11, cw = col & 2047;  // part is block-uniform (n0 mult of 128)
    int h = cw >> 7, d = cw & 127;
    if (part < 2) {
      // fused RoPE on fp32 acc; pair partner is lane l15^1
      bf16* dst = (part == 0) ? Qb : Kb;
      float invf = expf(-9.210340371976184f * (float)(d & ~1) * (1.0f / 128.0f));
      bool isodd = (d & 1) != 0;
      const float qscale = 0.08838834764831845f * 1.4426950408889634f;  // DH^-0.5 * log2(e)
      float sc = (part == 0) ? qscale : 1.0f;
      for (int i = 0; i < 4; i++) {
        int mrow = m0 + wm + i * 16 + quad * 4;
        for (int r = 0; r < 4; r++) {
          int m = mrow + r;
          int b = m >> 11, s = m & 2047;
          float v = acc[i][j][r];
          float p = __shfl_xor(v, 1, 64);  // partner element of the d-pair (same s)
          float sn, cs;
          sincosf((float)s * invf, &sn, &cs);
          float o = isodd ? (p * sn + v * cs) : (v * cs - p * sn);
          int dd = (part == 1) ? ((((d >> 3) ^ (s & 7)) << 3) | (d & 7)) : d;
          dst[(((size_t)(b * NH + h)) * SEQ + s) * DH + dd] = (bf16)(o * sc);
        }
      }
    } else {
      // V: transposed+swizzled direct write (B,H,DH,S layout, 64-col windows).
      // Within an r-run of 4: same b, same s&~63, same (s>>3)&7 -> bf16x4 store.
      for (int i = 0; i < 4; i++) {
        int mrow = m0 + wm + i * 16 + quad * 4;
        int b = mrow >> 11, s = mrow & 2047;
        int scol = (s & ~63) | (((((s >> 3) & 7) ^ (d & 7)) << 3) | (s & 7));
        bf16x4 pk;
        for (int r = 0; r < 4; r++) pk[r] = (bf16)acc[i][j][r];
        *(bf16x4*)&Vt[((size_t)(b * NH + h) * DH + d) * SEQ + scol] = pk;
      }
    }
  }
}

// ---------------- flash attention v5: counted-vmcnt pipeline + setprio ----------------
// Q-tile 64 (4 waves x 16 q-rows), K-tile 64 dbuf, 2 blocks/CU. Counted-vmcnt
// gates (round 3, race-free): top vmcnt(4)+barrier gates K(it); PV vmcnt(8)
// +barrier gates V(it) while K/V(it+1) stay in flight.
__global__ __launch_bounds__(256, 2) void attn_k(const bf16* __restrict__ Qb, const bf16* __restrict__ Kb,
                                                 const bf16* __restrict__ Vt, bf16* __restrict__ Yb) {
  __shared__ __align__(16) bf16 Ks[2][64 * 128];
  __shared__ __align__(16) bf16 Vs[2][128 * 64];
  __shared__ __align__(16) bf16 Pl[4][16 * 76];
  int bh = blockIdx.x;
  int slot = blockIdx.y;
  int w = threadIdx.x >> 6, l = threadIdx.x & 63;
  int l15 = l & 15, quad = l >> 4;
  const bf16* Qp = Qb + (size_t)bh * SEQ * DH;
  const bf16* Kp = Kb + (size_t)bh * SEQ * DH;
  const bf16* Vp = Vt + (size_t)bh * DH * SEQ;
  int b = bh >> 4, h = bh & 15;
  f32x4 zero = {0.f, 0.f, 0.f, 0.f};
  bf16* P = &Pl[w][0];

  auto stage = [&](int it, int buf) {
    const char* gk = (const char*)Kp + (size_t)it * 16384 + w * 4096 + l * 16;
    char* lk = (char*)&Ks[buf][0] + w * 4096;
    for (int i = 0; i < 4; i++) async16(gk + i * 1024, lk + i * 1024);
    const char* gv = (const char*)Vp + (size_t)it * 128 + (size_t)(w * 32 + (l >> 3)) * (SEQ * 2) + (l & 7) * 16;
    char* lv = (char*)&Vs[buf][0] + w * 32 * 128;
    for (int i = 0; i < 4; i++) async16(gv + (size_t)i * 8 * (SEQ * 2), lv + i * 1024);
  };

  int tiles[2] = {31 - slot, slot};
  for (int half = 0; half < 2; half++) {
    int tile = tiles[half];
    int qw = tile * 64 + w * 16;  // this wave's 16 q rows
    bf16x8 qf[4];
    for (int kc = 0; kc < 4; kc++)
      qf[kc] = *(const bf16x8*)&Qp[(size_t)(qw + l15) * DH + kc * 32 + quad * 8];
    f32x4 o[8];
    for (int ns = 0; ns < 8; ns++) o[ns] = zero;
    float mprev = -1e30f, lsum = 0.f;
    int nkt = tile + 1;

    stage(0, 0);
    __syncthreads();
    for (int it = 0; it < nkt; it++) {
      int buf = it & 1;
      bool more = (it + 1 < nkt);
      // top gate: own K(it) retired (outstanding = K(it)4+V(it)4 -> 4), then
      // collective barrier: all waves' K(it) landed; buf^1 readers done.
      asm volatile("s_waitcnt vmcnt(4)" ::: "memory");
      __builtin_amdgcn_s_barrier();
      __builtin_amdgcn_sched_barrier(0);
      if (more) stage(it + 1, buf ^ 1);
      int k0 = it * 64;
      // S^T = K(row) x Q(col=l15=q)
      f32x4 st[4];
      for (int ns = 0; ns < 4; ns++) st[ns] = zero;
      __builtin_amdgcn_s_setprio(1);
      for (int kc = 0; kc < 4; kc++)
        for (int ns = 0; ns < 4; ns++) {
          bf16x8 kf = *(const bf16x8*)&Ks[buf][(ns * 16 + l15) * 128 + (((kc * 4 + quad) ^ (l15 & 7)) << 3)];
          st[ns] = mfma16(kf, qf[kc], st[ns]);
        }
      __builtin_amdgcn_s_setprio(0);
      int qq = qw + l15;
      if (k0 + 63 > qw) {  // diagonal tile: mask k > q
        for (int ns = 0; ns < 4; ns++) {
          int kk = k0 + ns * 16 + quad * 4;
          for (int r = 0; r < 4; r++)
            if (kk + r > qq) st[ns][r] = -1e30f;
        }
      }
      float pm = -1e30f;
      for (int ns = 0; ns < 4; ns++)
        for (int r = 0; r < 4; r++) pm = fmaxf(pm, st[ns][r]);
      pm = fmaxf(pm, __shfl_xor(pm, 16, 64));
      pm = fmaxf(pm, __shfl_xor(pm, 32, 64));
      float mnew = fmaxf(mprev, pm);
      float al = exp2f(mprev - mnew);
      mprev = mnew;
      float ps = 0.f;
      for (int ns = 0; ns < 4; ns++)
        for (int r = 0; r < 4; r++) {
          float e = exp2f(st[ns][r] - mnew);
          st[ns][r] = e;
          ps += e;
        }
      ps += __shfl_xor(ps, 16, 64);
      ps += __shfl_xor(ps, 32, 64);
      lsum = lsum * al + ps;
      for (int ns = 0; ns < 8; ns++) o[ns] *= al;
      // P^T (C-layout) -> P[q][k] rows: lane holds k=quad*4..+3 contiguous -> b64 writes
      for (int ns = 0; ns < 4; ns++) {
        bf16x4 pk;
        for (int r = 0; r < 4; r++) pk[r] = (bf16)st[ns][r];
        *(bf16x4*)&P[l15 * 76 + ns * 16 + quad * 4] = pk;
      }
      asm volatile("s_waitcnt lgkmcnt(0)" ::: "memory");
      bf16x8 pa[2];
      for (int kc = 0; kc < 2; kc++)
        pa[kc] = *(const bf16x8*)&P[l15 * 76 + kc * 32 + quad * 8];
      // PV gate: own V(it) retired (K/V(it+1) = 8 newer loads stay in flight),
      // then collective barrier -> all waves' V(it) landed.
      if (more) {
        asm volatile("s_waitcnt vmcnt(8)" ::: "memory");
      } else {
        asm volatile("s_waitcnt vmcnt(0)" ::: "memory");
      }
      __builtin_amdgcn_s_barrier();
      __builtin_amdgcn_sched_barrier(0);
      __builtin_amdgcn_s_setprio(1);
      for (int ns = 0; ns < 8; ns++)
        for (int kc = 0; kc < 2; kc++) {
          bf16x8 vf = *(const bf16x8*)&Vs[buf][(ns * 16 + l15) * 64 + (((kc * 4 + quad) ^ (l15 & 7)) << 3)];
          o[ns] = mfma16(vf, pa[kc], o[ns]);  // O^T: col=l15=q
        }
      __builtin_amdgcn_s_setprio(0);
    }
    __syncthreads();  // half-boundary: all reads done before next half's restage
    // epilogue: O^T col=l15=q, row(within ns)=quad*4+r -> d = ns*16+quad*4+r
    float inv = 1.0f / lsum;
    int q = qw + l15;
    size_t base = ((size_t)(b * SEQ + q)) * DIN + h * DH + quad * 4;
    for (int ns = 0; ns < 8; ns++) {
      bf16x4 pk;
      for (int r = 0; r < 4; r++) pk[r] = (bf16)(o[ns][r] * inv);
      *(bf16x4*)&Yb[base + ns * 16] = pk;
    }
  }
}

// ---------------- proj GEMM (BK=64, xor-swizzled LDS chunks) ----------------
__global__ __launch_bounds__(256) void gemm_proj_k(const bf16* __restrict__ A, const bf16* __restrict__ BT,
                                                   void* __restrict__ out, const int* __restrict__ flag) {
  __shared__ __align__(16) bf16 As[128 * 64];
  __shared__ __align__(16) bf16 Bs[128 * 64];
  const int K = DIN;
  int m0 = blockIdx.y * 128, n0 = blockIdx.x * 128;
  int tid = threadIdx.x, w = tid >> 6, l = tid & 63;
  int l15 = l & 15, quad = l >> 4;
  int wm = (w & 1) * 64, wn = (w >> 1) * 64;
  bool obf = *flag != 0;
  f32x4 zero = {0.f, 0.f, 0.f, 0.f};
  f32x4 acc[4][4];
  for (int i = 0; i < 4; i++)
    for (int j = 0; j < 4; j++) acc[i][j] = zero;
  int gch = (l & 7) ^ (l >> 3);
  const bf16* Ag = A + (size_t)(m0 + w * 32 + (l >> 3)) * K + gch * 8;
  const bf16* Bg = BT + (size_t)(n0 + w * 32 + (l >> 3)) * K + gch * 8;
  bf16* AsW = As + w * 2048;
  bf16* BsW = Bs + w * 2048;
  for (int k0 = 0; k0 < K; k0 += 64) {
    __syncthreads();
    for (int j = 0; j < 4; j++) async16(Ag + k0 + (size_t)j * 8 * K, AsW + j * 512);
    for (int j = 0; j < 4; j++) async16(Bg + k0 + (size_t)j * 8 * K, BsW + j * 512);
    __syncthreads();
    for (int kk = 0; kk < 2; kk++) {
      bf16x8 af[4], bfv[4];
      for (int i = 0; i < 4; i++)
        af[i] = *(const bf16x8*)&As[(wm + i * 16 + l15) * 64 + (((kk * 4 + quad) ^ (l15 & 7)) << 3)];
      for (int j = 0; j < 4; j++)
        bfv[j] = *(const bf16x8*)&Bs[(wn + j * 16 + l15) * 64 + (((kk * 4 + quad) ^ (l15 & 7)) << 3)];
      for (int i = 0; i < 4; i++)
        for (int j = 0; j < 4; j++) acc[i][j] = mfma16(af[i], bfv[j], acc[i][j]);
    }
  }
  for (int j = 0; j < 4; j++) {
    int col = n0 + wn + j * 16 + l15;
    for (int i = 0; i < 4; i++) {
      int mrow = m0 + wm + i * 16 + quad * 4;
      for (int r = 0; r < 4; r++) {
        size_t idx = (size_t)(mrow + r) * DIN + col;
        float v = acc[i][j][r];
        if (obf)
          ((bf16*)out)[idx] = (bf16)v;
        else
          ((float*)out)[idx] = v;
      }
    }
  }
}

extern "C" void kernel_launch(void* const* d_in, const int* in_sizes, int n_in,
                              void* d_out, int out_size, void* d_ws, size_t ws_size,
                              hipStream_t stream) {
  char* ws = (char*)d_ws;
  int* flag = (int*)ws;
  bf16* Xb = (bf16*)(ws + 256);                                  // 16 MiB, aliased with Yb
  bf16* WqkvT = (bf16*)(ws + 256 + 16777216);                    // 24 MiB
  bf16* WprojT = (bf16*)(ws + 256 + 16777216 + 25165824);        // 8 MiB
  bf16* Qb = (bf16*)(ws + 256 + 16777216 + 25165824 + 8388608);  // 16 MiB each
  bf16* Kb = Qb + (size_t)MM * DIN;
  bf16* Vb = Kb + (size_t)MM * DIN;  // unused (V written transposed directly)
  bf16* Vt = Vb + (size_t)MM * DIN;
  bf16* Yb = Xb;  // Xb dead after gemm_qkv

  sniff_k<<<1, 256, 0, stream>>>((const unsigned short*)d_in[0], flag);
  cast_x_k<<<4096, 256, 0, stream>>>(d_in[0], Xb, flag);
  cast_wT_k<<<dim3(192, 64), 256, 0, stream>>>(d_in[1], WqkvT, flag, DIN, N3);
  cast_wT_k<<<dim3(64, 64), 256, 0, stream>>>(d_in[2], WprojT, flag, DIN, DIN);
  gemm_qkv_k<<<dim3(48, 16), 256, 0, stream>>>(Xb, WqkvT, Qb, Kb, Vt, 0);
  gemm_qkv_k<<<dim3(48, 16), 256, 0, stream>>>(Xb, WqkvT, Qb, Kb, Vt, 2048);
  attn_k<<<dim3(32, 16), 256, 0, stream>>>(Qb, Kb, Vt, Yb);
  gemm_proj_k<<<dim3(16, 32), 256, 0, stream>>>(Yb, WprojT, d_out, flag);
}

// Round 6
// 419.528 us; speedup vs baseline: 1.9149x; 1.9149x over previous
//
#include <hip/hip_runtime.h>

#define DIN 2048
#define NH 16
#define DH 128
#define SEQ 2048
#define BB 2
#define N3 6144
#define MM 4096  // BB*SEQ

typedef __bf16 bf16;
typedef __attribute__((ext_vector_type(8))) __bf16 bf16x8;
typedef __attribute__((ext_vector_type(4))) __bf16 bf16x4;
typedef __attribute__((ext_vector_type(2))) __bf16 bf16x2;
typedef __attribute__((ext_vector_type(4))) float f32x4;

__device__ __forceinline__ f32x4 mfma16(bf16x8 a, bf16x8 b, f32x4 c) {
  return __builtin_amdgcn_mfma_f32_16x16x32_bf16(a, b, c, 0, 0, 0);
}

__device__ __forceinline__ void async16(const void* g, void* l) {
  __builtin_amdgcn_global_load_lds((const __attribute__((address_space(1))) void*)g,
                                   (__attribute__((address_space(3))) void*)l, 16, 0, 0);
}

// ---------------- dtype sniff ----------------
__global__ void sniff_k(const unsigned short* __restrict__ x, int* __restrict__ flag) {
  __shared__ int cnt;
  if (threadIdx.x == 0) cnt = 0;
  __syncthreads();
  unsigned short u = x[threadIdx.x * 2];
  int e = (u >> 7) & 0xff;
  if (e >= 108 && e <= 140) atomicAdd(&cnt, 1);
  __syncthreads();
  if (threadIdx.x == 0) *flag = (cnt >= 128) ? 1 : 0;
}

// ---------------- RoPE trig LUT: trig[s][d2] = {cos, sin} of s*invf(2*d2) ----
// 2048*64 float2 = 1 MB; computed once (sincosf is fine here: 1 call/thread,
// nothing live across it). Consumed by gemm_qkv's fused-RoPE epilogue --
// calling sincosf THERE spilled acc[4][4] around each non-inlined ocml call
// (round-5 post-mortem: 1.45 GB scratch writes, 278 us/half).
__global__ __launch_bounds__(256) void trig_k(float2* __restrict__ trig) {
  int i = blockIdx.x * 256 + threadIdx.x;  // s*64 + d2
  int d2 = i & 63, s = i >> 6;
  float invf = expf(-9.210340371976184f * (float)(2 * d2) * (1.0f / 128.0f));
  float sn, cs;
  sincosf((float)s * invf, &sn, &cs);
  trig[i] = make_float2(cs, sn);
}

// ---------------- casts ----------------
__global__ __launch_bounds__(256) void cast_x_k(const void* __restrict__ in, bf16* __restrict__ out,
                                                const int* __restrict__ flag) {
  size_t i = ((size_t)blockIdx.x * 256 + threadIdx.x) * 8;
  if (*flag) {
    *(bf16x8*)(out + i) = *(const bf16x8*)((const bf16*)in + i);
  } else {
    const float* f = (const float*)in;
    bf16x8 v;
    for (int j = 0; j < 8; j++) v[j] = (bf16)f[i + j];
    *(bf16x8*)(out + i) = v;
  }
}

// 32x32 transpose tile; write phase emits 4B bf16x2 pairs (2x wider than scalar).
__global__ __launch_bounds__(256) void cast_wT_k(const void* __restrict__ in, bf16* __restrict__ out,
                                                 const int* __restrict__ flag, int R, int C) {
  __shared__ float t[32][33];
  int c0 = blockIdx.x * 32, r0 = blockIdx.y * 32;
  int tx = threadIdx.x & 31, ty = threadIdx.x >> 5;
  bool isb = *flag != 0;
  for (int j = 0; j < 4; j++) {
    int r = ty + j * 8;
    size_t idx = (size_t)(r0 + r) * C + c0 + tx;
    float v = isb ? (float)((const bf16*)in)[idx] : ((const float*)in)[idx];
    t[r][tx] = v;
  }
  __syncthreads();
  int tx8 = threadIdx.x & 15;  // row-pair index: rows 2*tx8, 2*tx8+1
  int cy = threadIdx.x >> 4;   // 0..15
  for (int j = 0; j < 2; j++) {
    int c = cy + j * 16;
    bf16x2 v;
    v[0] = (bf16)t[2 * tx8][c];
    v[1] = (bf16)t[2 * tx8 + 1][c];
    *(bf16x2*)&out[(size_t)(c0 + c) * R + r0 + 2 * tx8] = v;
  }
}

// ---------------- qkv GEMM (proven 128x128, BK=64, xor-swizzled chunks) ----
// Two M-half dispatches (each 48x16 = 768 blocks = exactly 3.0 rounds; zero
// tail) -- keeps the rocprof top-5 floor at ~60 us for visibility. Epilogue:
//  * V transpose+swizzle direct write (B,H,DH,S), bf16x4 stores
//  * RoPE for Q/K on fp32 acc via the trig LUT (NO sincosf calls -> no spill;
//    pair partner = lane l15^1 via shfl_xor, same LUT entry since d,d^1 share
//    d>>1); Q gets DH^-0.5 * log2(e) folded in (scores in log2 domain);
//    K rows carry the 16B-chunk xor swizzle consumed by attn's DMA staging.
__global__ __launch_bounds__(256) void gemm_qkv_k(const bf16* __restrict__ A, const bf16* __restrict__ BT,
                                                  bf16* __restrict__ Qb, bf16* __restrict__ Kb,
                                                  bf16* __restrict__ Vt,
                                                  const float2* __restrict__ trig, int m0base) {
  __shared__ __align__(16) bf16 As[128 * 64];
  __shared__ __align__(16) bf16 Bs[128 * 64];
  const int K = DIN;
  int m0 = m0base + blockIdx.y * 128, n0 = blockIdx.x * 128;
  int tid = threadIdx.x, w = tid >> 6, l = tid & 63;
  int l15 = l & 15, quad = l >> 4;
  int wm = (w & 1) * 64, wn = (w >> 1) * 64;
  f32x4 zero = {0.f, 0.f, 0.f, 0.f};
  f32x4 acc[4][4];
  for (int i = 0; i < 4; i++)
    for (int j = 0; j < 4; j++) acc[i][j] = zero;
  int gch = (l & 7) ^ (l >> 3);  // swizzled source chunk for this lane
  const bf16* Ag = A + (size_t)(m0 + w * 32 + (l >> 3)) * K + gch * 8;
  const bf16* Bg = BT + (size_t)(n0 + w * 32 + (l >> 3)) * K + gch * 8;
  bf16* AsW = As + w * 2048;  // wave stages rows w*32..+31 (4 KB)
  bf16* BsW = Bs + w * 2048;
  for (int k0 = 0; k0 < K; k0 += 64) {
    __syncthreads();
    for (int j = 0; j < 4; j++) async16(Ag + k0 + (size_t)j * 8 * K, AsW + j * 512);
    for (int j = 0; j < 4; j++) async16(Bg + k0 + (size_t)j * 8 * K, BsW + j * 512);
    __syncthreads();
    for (int kk = 0; kk < 2; kk++) {
      bf16x8 af[4], bfv[4];
      for (int i = 0; i < 4; i++)
        af[i] = *(const bf16x8*)&As[(wm + i * 16 + l15) * 64 + (((kk * 4 + quad) ^ (l15 & 7)) << 3)];
      for (int j = 0; j < 4; j++)
        bfv[j] = *(const bf16x8*)&Bs[(wn + j * 16 + l15) * 64 + (((kk * 4 + quad) ^ (l15 & 7)) << 3)];
      for (int i = 0; i < 4; i++)
        for (int j = 0; j < 4; j++) acc[i][j] = mfma16(af[i], bfv[j], acc[i][j]);
    }
  }
  for (int j = 0; j < 4; j++) {
    int col = n0 + wn + j * 16 + l15;
    int part = col >> 11, cw = col & 2047;  // part is block-uniform (n0 mult of 128)
    int h = cw >> 7, d = cw & 127;
    if (part < 2) {
      // fused RoPE on fp32 acc; pair partner is lane l15^1; trig from LUT
      bf16* dst = (part == 0) ? Qb : Kb;
      int d2 = d >> 1;
      bool isodd = (d & 1) != 0;
      const float qscale = 0.08838834764831845f * 1.4426950408889634f;  // DH^-0.5 * log2(e)
      float sc = (part == 0) ? qscale : 1.0f;
      for (int i = 0; i < 4; i++) {
        int mrow = m0 + wm + i * 16 + quad * 4;
        for (int r = 0; r < 4; r++) {
          int m = mrow + r;
          int b = m >> 11, s = m & 2047;
          float v = acc[i][j][r];
          float p = __shfl_xor(v, 1, 64);  // partner element of the d-pair (same s)
          float2 t = trig[(s << 6) + d2];
          float o = isodd ? (p * t.y + v * t.x) : (v * t.x - p * t.y);
          int dd = (part == 1) ? ((((d >> 3) ^ (s & 7)) << 3) | (d & 7)) : d;
          dst[(((size_t)(b * NH + h)) * SEQ + s) * DH + dd] = (bf16)(o * sc);
        }
      }
    } else {
      // V: transposed+swizzled direct write (B,H,DH,S layout, 64-col windows).
      // Within an r-run of 4: same b, same s&~63, same (s>>3)&7 -> bf16x4 store.
      for (int i = 0; i < 4; i++) {
        int mrow = m0 + wm + i * 16 + quad * 4;
        int b = mrow >> 11, s = mrow & 2047;
        int scol = (s & ~63) | (((((s >> 3) & 7) ^ (d & 7)) << 3) | (s & 7));
        bf16x4 pk;
        for (int r = 0; r < 4; r++) pk[r] = (bf16)acc[i][j][r];
        *(bf16x4*)&Vt[((size_t)(b * NH + h) * DH + d) * SEQ + scol] = pk;
      }
    }
  }
}

// ---------------- flash attention v5: counted-vmcnt pipeline + setprio ----------------
// Q-tile 64 (4 waves x 16 q-rows), K-tile 64 dbuf, 2 blocks/CU. Counted-vmcnt
// gates (round 3, race-free): top vmcnt(4)+barrier gates K(it); PV vmcnt(8)
// +barrier gates V(it) while K/V(it+1) stay in flight.
__global__ __launch_bounds__(256, 2) void attn_k(const bf16* __restrict__ Qb, const bf16* __restrict__ Kb,
                                                 const bf16* __restrict__ Vt, bf16* __restrict__ Yb) {
  __shared__ __align__(16) bf16 Ks[2][64 * 128];
  __shared__ __align__(16) bf16 Vs[2][128 * 64];
  __shared__ __align__(16) bf16 Pl[4][16 * 76];
  int bh = blockIdx.x;
  int slot = blockIdx.y;
  int w = threadIdx.x >> 6, l = threadIdx.x & 63;
  int l15 = l & 15, quad = l >> 4;
  const bf16* Qp = Qb + (size_t)bh * SEQ * DH;
  const bf16* Kp = Kb + (size_t)bh * SEQ * DH;
  const bf16* Vp = Vt + (size_t)bh * DH * SEQ;
  int b = bh >> 4, h = bh & 15;
  f32x4 zero = {0.f, 0.f, 0.f, 0.f};
  bf16* P = &Pl[w][0];

  auto stage = [&](int it, int buf) {
    const char* gk = (const char*)Kp + (size_t)it * 16384 + w * 4096 + l * 16;
    char* lk = (char*)&Ks[buf][0] + w * 4096;
    for (int i = 0; i < 4; i++) async16(gk + i * 1024, lk + i * 1024);
    const char* gv = (const char*)Vp + (size_t)it * 128 + (size_t)(w * 32 + (l >> 3)) * (SEQ * 2) + (l & 7) * 16;
    char* lv = (char*)&Vs[buf][0] + w * 32 * 128;
    for (int i = 0; i < 4; i++) async16(gv + (size_t)i * 8 * (SEQ * 2), lv + i * 1024);
  };

  int tiles[2] = {31 - slot, slot};
  for (int half = 0; half < 2; half++) {
    int tile = tiles[half];
    int qw = tile * 64 + w * 16;  // this wave's 16 q rows
    bf16x8 qf[4];
    for (int kc = 0; kc < 4; kc++)
      qf[kc] = *(const bf16x8*)&Qp[(size_t)(qw + l15) * DH + kc * 32 + quad * 8];
    f32x4 o[8];
    for (int ns = 0; ns < 8; ns++) o[ns] = zero;
    float mprev = -1e30f, lsum = 0.f;
    int nkt = tile + 1;

    stage(0, 0);
    __syncthreads();
    for (int it = 0; it < nkt; it++) {
      int buf = it & 1;
      bool more = (it + 1 < nkt);
      // top gate: own K(it) retired (outstanding = K(it)4+V(it)4 -> 4), then
      // collective barrier: all waves' K(it) landed; buf^1 readers done.
      asm volatile("s_waitcnt vmcnt(4)" ::: "memory");
      __builtin_amdgcn_s_barrier();
      __builtin_amdgcn_sched_barrier(0);
      if (more) stage(it + 1, buf ^ 1);
      int k0 = it * 64;
      // S^T = K(row) x Q(col=l15=q)
      f32x4 st[4];
      for (int ns = 0; ns < 4; ns++) st[ns] = zero;
      __builtin_amdgcn_s_setprio(1);
      for (int kc = 0; kc < 4; kc++)
        for (int ns = 0; ns < 4; ns++) {
          bf16x8 kf = *(const bf16x8*)&Ks[buf][(ns * 16 + l15) * 128 + (((kc * 4 + quad) ^ (l15 & 7)) << 3)];
          st[ns] = mfma16(kf, qf[kc], st[ns]);
        }
      __builtin_amdgcn_s_setprio(0);
      int qq = qw + l15;
      if (k0 + 63 > qw) {  // diagonal tile: mask k > q
        for (int ns = 0; ns < 4; ns++) {
          int kk = k0 + ns * 16 + quad * 4;
          for (int r = 0; r < 4; r++)
            if (kk + r > qq) st[ns][r] = -1e30f;
        }
      }
      float pm = -1e30f;
      for (int ns = 0; ns < 4; ns++)
        for (int r = 0; r < 4; r++) pm = fmaxf(pm, st[ns][r]);
      pm = fmaxf(pm, __shfl_xor(pm, 16, 64));
      pm = fmaxf(pm, __shfl_xor(pm, 32, 64));
      float mnew = fmaxf(mprev, pm);
      float al = exp2f(mprev - mnew);
      mprev = mnew;
      float ps = 0.f;
      for (int ns = 0; ns < 4; ns++)
        for (int r = 0; r < 4; r++) {
          float e = exp2f(st[ns][r] - mnew);
          st[ns][r] = e;
          ps += e;
        }
      ps += __shfl_xor(ps, 16, 64);
      ps += __shfl_xor(ps, 32, 64);
      lsum = lsum * al + ps;
      for (int ns = 0; ns < 8; ns++) o[ns] *= al;
      // P^T (C-layout) -> P[q][k] rows: lane holds k=quad*4..+3 contiguous -> b64 writes
      for (int ns = 0; ns < 4; ns++) {
        bf16x4 pk;
        for (int r = 0; r < 4; r++) pk[r] = (bf16)st[ns][r];
        *(bf16x4*)&P[l15 * 76 + ns * 16 + quad * 4] = pk;
      }
      asm volatile("s_waitcnt lgkmcnt(0)" ::: "memory");
      bf16x8 pa[2];
      for (int kc = 0; kc < 2; kc++)
        pa[kc] = *(const bf16x8*)&P[l15 * 76 + kc * 32 + quad * 8];
      // PV gate: own V(it) retired (K/V(it+1) = 8 newer loads stay in flight),
      // then collective barrier -> all waves' V(it) landed.
      if (more) {
        asm volatile("s_waitcnt vmcnt(8)" ::: "memory");
      } else {
        asm volatile("s_waitcnt vmcnt(0)" ::: "memory");
      }
      __builtin_amdgcn_s_barrier();
      __builtin_amdgcn_sched_barrier(0);
      __builtin_amdgcn_s_setprio(1);
      for (int ns = 0; ns < 8; ns++)
        for (int kc = 0; kc < 2; kc++) {
          bf16x8 vf = *(const bf16x8*)&Vs[buf][(ns * 16 + l15) * 64 + (((kc * 4 + quad) ^ (l15 & 7)) << 3)];
          o[ns] = mfma16(vf, pa[kc], o[ns]);  // O^T: col=l15=q
        }
      __builtin_amdgcn_s_setprio(0);
    }
    __syncthreads();  // half-boundary: all reads done before next half's restage
    // epilogue: O^T col=l15=q, row(within ns)=quad*4+r -> d = ns*16+quad*4+r
    float inv = 1.0f / lsum;
    int q = qw + l15;
    size_t base = ((size_t)(b * SEQ + q)) * DIN + h * DH + quad * 4;
    for (int ns = 0; ns < 8; ns++) {
      bf16x4 pk;
      for (int r = 0; r < 4; r++) pk[r] = (bf16)(o[ns][r] * inv);
      *(bf16x4*)&Yb[base + ns * 16] = pk;
    }
  }
}

// ---------------- proj GEMM (BK=64, xor-swizzled LDS chunks) ----------------
__global__ __launch_bounds__(256) void gemm_proj_k(const bf16* __restrict__ A, const bf16* __restrict__ BT,
                                                   void* __restrict__ out, const int* __restrict__ flag) {
  __shared__ __align__(16) bf16 As[128 * 64];
  __shared__ __align__(16) bf16 Bs[128 * 64];
  const int K = DIN;
  int m0 = blockIdx.y * 128, n0 = blockIdx.x * 128;
  int tid = threadIdx.x, w = tid >> 6, l = tid & 63;
  int l15 = l & 15, quad = l >> 4;
  int wm = (w & 1) * 64, wn = (w >> 1) * 64;
  bool obf = *flag != 0;
  f32x4 zero = {0.f, 0.f, 0.f, 0.f};
  f32x4 acc[4][4];
  for (int i = 0; i < 4; i++)
    for (int j = 0; j < 4; j++) acc[i][j] = zero;
  int gch = (l & 7) ^ (l >> 3);
  const bf16* Ag = A + (size_t)(m0 + w * 32 + (l >> 3)) * K + gch * 8;
  const bf16* Bg = BT + (size_t)(n0 + w * 32 + (l >> 3)) * K + gch * 8;
  bf16* AsW = As + w * 2048;
  bf16* BsW = Bs + w * 2048;
  for (int k0 = 0; k0 < K; k0 += 64) {
    __syncthreads();
    for (int j = 0; j < 4; j++) async16(Ag + k0 + (size_t)j * 8 * K, AsW + j * 512);
    for (int j = 0; j < 4; j++) async16(Bg + k0 + (size_t)j * 8 * K, BsW + j * 512);
    __syncthreads();
    for (int kk = 0; kk < 2; kk++) {
      bf16x8 af[4], bfv[4];
      for (int i = 0; i < 4; i++)
        af[i] = *(const bf16x8*)&As[(wm + i * 16 + l15) * 64 + (((kk * 4 + quad) ^ (l15 & 7)) << 3)];
      for (int j = 0; j < 4; j++)
        bfv[j] = *(const bf16x8*)&Bs[(wn + j * 16 + l15) * 64 + (((kk * 4 + quad) ^ (l15 & 7)) << 3)];
      for (int i = 0; i < 4; i++)
        for (int j = 0; j < 4; j++) acc[i][j] = mfma16(af[i], bfv[j], acc[i][j]);
    }
  }
  for (int j = 0; j < 4; j++) {
    int col = n0 + wn + j * 16 + l15;
    for (int i = 0; i < 4; i++) {
      int mrow = m0 + wm + i * 16 + quad * 4;
      for (int r = 0; r < 4; r++) {
        size_t idx = (size_t)(mrow + r) * DIN + col;
        float v = acc[i][j][r];
        if (obf)
          ((bf16*)out)[idx] = (bf16)v;
        else
          ((float*)out)[idx] = v;
      }
    }
  }
}

extern "C" void kernel_launch(void* const* d_in, const int* in_sizes, int n_in,
                              void* d_out, int out_size, void* d_ws, size_t ws_size,
                              hipStream_t stream) {
  char* ws = (char*)d_ws;
  int* flag = (int*)ws;
  bf16* Xb = (bf16*)(ws + 256);                                  // 16 MiB, aliased with Yb
  bf16* WqkvT = (bf16*)(ws + 256 + 16777216);                    // 24 MiB
  bf16* WprojT = (bf16*)(ws + 256 + 16777216 + 25165824);        // 8 MiB
  bf16* Qb = (bf16*)(ws + 256 + 16777216 + 25165824 + 8388608);  // 16 MiB each
  bf16* Kb = Qb + (size_t)MM * DIN;
  bf16* Vb = Kb + (size_t)MM * DIN;  // V slot reused: RoPE trig LUT (1 MiB)
  bf16* Vt = Vb + (size_t)MM * DIN;
  bf16* Yb = Xb;  // Xb dead after gemm_qkv
  float2* trig = (float2*)Vb;

  sniff_k<<<1, 256, 0, stream>>>((const unsigned short*)d_in[0], flag);
  trig_k<<<512, 256, 0, stream>>>(trig);
  cast_x_k<<<4096, 256, 0, stream>>>(d_in[0], Xb, flag);
  cast_wT_k<<<dim3(192, 64), 256, 0, stream>>>(d_in[1], WqkvT, flag, DIN, N3);
  cast_wT_k<<<dim3(64, 64), 256, 0, stream>>>(d_in[2], WprojT, flag, DIN, DIN);
  gemm_qkv_k<<<dim3(48, 16), 256, 0, stream>>>(Xb, WqkvT, Qb, Kb, Vt, trig, 0);
  gemm_qkv_k<<<dim3(48, 16), 256, 0, stream>>>(Xb, WqkvT, Qb, Kb, Vt, trig, 2048);
  attn_k<<<dim3(32, 16), 256, 0, stream>>>(Qb, Kb, Vt, Yb);
  gemm_proj_k<<<dim3(16, 32), 256, 0, stream>>>(Yb, WprojT, d_out, flag);
}

// Round 7
// 396.820 us; speedup vs baseline: 2.0244x; 1.0572x over previous
//
#include <hip/hip_runtime.h>

#define DIN 2048
#define NH 16
#define DH 128
#define SEQ 2048
#define BB 2
#define N3 6144
#define MM 4096  // BB*SEQ

typedef __bf16 bf16;
typedef __attribute__((ext_vector_type(8))) __bf16 bf16x8;
typedef __attribute__((ext_vector_type(4))) __bf16 bf16x4;
typedef __attribute__((ext_vector_type(2))) __bf16 bf16x2;
typedef __attribute__((ext_vector_type(4))) float f32x4;

__device__ __forceinline__ f32x4 mfma16(bf16x8 a, bf16x8 b, f32x4 c) {
  return __builtin_amdgcn_mfma_f32_16x16x32_bf16(a, b, c, 0, 0, 0);
}

__device__ __forceinline__ void async16(const void* g, void* l) {
  __builtin_amdgcn_global_load_lds((const __attribute__((address_space(1))) void*)g,
                                   (__attribute__((address_space(3))) void*)l, 16, 0, 0);
}

// ---------------- dtype sniff ----------------
__global__ void sniff_k(const unsigned short* __restrict__ x, int* __restrict__ flag) {
  __shared__ int cnt;
  if (threadIdx.x == 0) cnt = 0;
  __syncthreads();
  unsigned short u = x[threadIdx.x * 2];
  int e = (u >> 7) & 0xff;
  if (e >= 108 && e <= 140) atomicAdd(&cnt, 1);
  __syncthreads();
  if (threadIdx.x == 0) *flag = (cnt >= 128) ? 1 : 0;
}

// ---------------- RoPE trig LUT: trig[s][d2] = {cos, sin} of s*invf(2*d2) ----
// 2048*64 float2 = 1 MB; sincosf is fine HERE (1 call/thread, nothing live).
__global__ __launch_bounds__(256) void trig_k(float2* __restrict__ trig) {
  int i = blockIdx.x * 256 + threadIdx.x;  // s*64 + d2
  int d2 = i & 63, s = i >> 6;
  float invf = expf(-9.210340371976184f * (float)(2 * d2) * (1.0f / 128.0f));
  float sn, cs;
  sincosf((float)s * invf, &sn, &cs);
  trig[i] = make_float2(cs, sn);
}

// ---------------- casts ----------------
__global__ __launch_bounds__(256) void cast_x_k(const void* __restrict__ in, bf16* __restrict__ out,
                                                const int* __restrict__ flag) {
  size_t i = ((size_t)blockIdx.x * 256 + threadIdx.x) * 8;
  if (*flag) {
    *(bf16x8*)(out + i) = *(const bf16x8*)((const bf16*)in + i);
  } else {
    const float* f = (const float*)in;
    bf16x8 v;
    for (int j = 0; j < 8; j++) v[j] = (bf16)f[i + j];
    *(bf16x8*)(out + i) = v;
  }
}

// 32x32 transpose tile; write phase emits 4B bf16x2 pairs (2x wider than scalar).
__global__ __launch_bounds__(256) void cast_wT_k(const void* __restrict__ in, bf16* __restrict__ out,
                                                 const int* __restrict__ flag, int R, int C) {
  __shared__ float t[32][33];
  int c0 = blockIdx.x * 32, r0 = blockIdx.y * 32;
  int tx = threadIdx.x & 31, ty = threadIdx.x >> 5;
  bool isb = *flag != 0;
  for (int j = 0; j < 4; j++) {
    int r = ty + j * 8;
    size_t idx = (size_t)(r0 + r) * C + c0 + tx;
    float v = isb ? (float)((const bf16*)in)[idx] : ((const float*)in)[idx];
    t[r][tx] = v;
  }
  __syncthreads();
  int tx8 = threadIdx.x & 15;  // row-pair index: rows 2*tx8, 2*tx8+1
  int cy = threadIdx.x >> 4;   // 0..15
  for (int j = 0; j < 2; j++) {
    int c = cy + j * 16;
    bf16x2 v;
    v[0] = (bf16)t[2 * tx8][c];
    v[1] = (bf16)t[2 * tx8 + 1][c];
    *(bf16x2*)&out[(size_t)(c0 + c) * R + r0 + 2 * tx8] = v;
  }
}

// ---------------- qkv GEMM (round-4 proven: 128x128, BK=64, xor-swizzled chunks) ----
// Single dispatch, 1536 blocks = 6.0 rounds, 32 KiB LDS (5 blocks/CU), VGPR 92.
// Measured 119.5 us (~885 TF), the m97-structure ceiling. Epilogue fuses ONLY
// the V transpose+swizzle (bf16x4 stores); RoPE lives in rope_lut_k (round-6
// post-mortem: in-epilogue RoPE cost ~86 us via occupancy drop + 64 LUT loads
// + 64 ds_permute per thread).
__global__ __launch_bounds__(256) void gemm_qkv_k(const bf16* __restrict__ A, const bf16* __restrict__ BT,
                                                  bf16* __restrict__ Qb, bf16* __restrict__ Kb,
                                                  bf16* __restrict__ Vt) {
  __shared__ __align__(16) bf16 As[128 * 64];
  __shared__ __align__(16) bf16 Bs[128 * 64];
  const int K = DIN;
  int m0 = blockIdx.y * 128, n0 = blockIdx.x * 128;
  int tid = threadIdx.x, w = tid >> 6, l = tid & 63;
  int l15 = l & 15, quad = l >> 4;
  int wm = (w & 1) * 64, wn = (w >> 1) * 64;
  f32x4 zero = {0.f, 0.f, 0.f, 0.f};
  f32x4 acc[4][4];
  for (int i = 0; i < 4; i++)
    for (int j = 0; j < 4; j++) acc[i][j] = zero;
  int gch = (l & 7) ^ (l >> 3);  // swizzled source chunk for this lane
  const bf16* Ag = A + (size_t)(m0 + w * 32 + (l >> 3)) * K + gch * 8;
  const bf16* Bg = BT + (size_t)(n0 + w * 32 + (l >> 3)) * K + gch * 8;
  bf16* AsW = As + w * 2048;  // wave stages rows w*32..+31 (4 KB)
  bf16* BsW = Bs + w * 2048;
  for (int k0 = 0; k0 < K; k0 += 64) {
    __syncthreads();
    for (int j = 0; j < 4; j++) async16(Ag + k0 + (size_t)j * 8 * K, AsW + j * 512);
    for (int j = 0; j < 4; j++) async16(Bg + k0 + (size_t)j * 8 * K, BsW + j * 512);
    __syncthreads();
    for (int kk = 0; kk < 2; kk++) {
      bf16x8 af[4], bfv[4];
      for (int i = 0; i < 4; i++)
        af[i] = *(const bf16x8*)&As[(wm + i * 16 + l15) * 64 + (((kk * 4 + quad) ^ (l15 & 7)) << 3)];
      for (int j = 0; j < 4; j++)
        bfv[j] = *(const bf16x8*)&Bs[(wn + j * 16 + l15) * 64 + (((kk * 4 + quad) ^ (l15 & 7)) << 3)];
      for (int i = 0; i < 4; i++)
        for (int j = 0; j < 4; j++) acc[i][j] = mfma16(af[i], bfv[j], acc[i][j]);
    }
  }
  for (int j = 0; j < 4; j++) {
    int col = n0 + wn + j * 16 + l15;
    int part = col >> 11, cw = col & 2047;  // part is block-uniform (n0 mult of 128)
    int h = cw >> 7, d = cw & 127;
    if (part < 2) {
      bf16* dst = (part == 0) ? Qb : Kb;
      for (int i = 0; i < 4; i++) {
        int mrow = m0 + wm + i * 16 + quad * 4;
        for (int r = 0; r < 4; r++) {
          int m = mrow + r;
          int b = m >> 11, s = m & 2047;
          // K rows carry the 16B-chunk xor swizzle consumed by attn's DMA staging
          int dd = (part == 1) ? ((((d >> 3) ^ (s & 7)) << 3) | (d & 7)) : d;
          dst[(((size_t)(b * NH + h)) * SEQ + s) * DH + dd] = (bf16)acc[i][j][r];
        }
      }
    } else {
      // V: transposed+swizzled direct write (B,H,DH,S layout, 64-col windows).
      // Within an r-run of 4: same b, same s&~63, same (s>>3)&7 -> bf16x4 store.
      for (int i = 0; i < 4; i++) {
        int mrow = m0 + wm + i * 16 + quad * 4;
        int b = mrow >> 11, s = mrow & 2047;
        int scol = (s & ~63) | (((((s >> 3) & 7) ^ (d & 7)) << 3) | (s & 7));
        bf16x4 pk;
        for (int r = 0; r < 4; r++) pk[r] = (bf16)acc[i][j][r];
        *(bf16x4*)&Vt[((size_t)(b * NH + h) * DH + d) * SEQ + scol] = pk;
      }
    }
  }
}

// ---------------- RoPE via LUT: zero transcendentals, bf16x8 vector I/O ----------------
// Thread handles (bh, s, g): 8 contiguous elements 8g..8g+7 = 4 rotation pairs.
// Q: plain row offset 8g. K: gemm wrote chunk g at swizzled chunk g^(s&7) with
// low-3 bits preserved -> one contiguous bf16x8 at chunk (g^(s&7)). LUT entries
// (s, 4g..4g+3) = 32B coalesced. Q gets DH^-0.5 * log2(e) folded in.
// Replaces sincosf-based rope_k (round-6 accounting: ~60+ us of ocml calls).
__global__ __launch_bounds__(256) void rope_lut_k(bf16* __restrict__ Qb, bf16* __restrict__ Kb,
                                                  const float2* __restrict__ trig) {
  int i = blockIdx.x * 256 + threadIdx.x;  // (bh, s, g): 32*2048*16
  int g = i & 15;
  int s = (i >> 4) & 2047;
  int bh = i >> 15;
  size_t row = ((size_t)bh * SEQ + s) * DH;
  float2 tt[4];
  for (int p = 0; p < 4; p++) tt[p] = trig[(s << 6) + 4 * g + p];
  const float qscale = 0.08838834764831845f * 1.4426950408889634f;  // DH^-0.5 * log2(e)
  // Q
  {
    bf16* qp = Qb + row + 8 * g;
    bf16x8 v = *(const bf16x8*)qp;
    bf16x8 o;
#pragma unroll
    for (int p = 0; p < 4; p++) {
      float e = (float)v[2 * p], od = (float)v[2 * p + 1];
      o[2 * p] = (bf16)((e * tt[p].x - od * tt[p].y) * qscale);
      o[2 * p + 1] = (bf16)((e * tt[p].y + od * tt[p].x) * qscale);
    }
    *(bf16x8*)qp = o;
  }
  // K (swizzled chunk)
  {
    bf16* kp = Kb + row + ((g ^ (s & 7)) << 3);
    bf16x8 v = *(const bf16x8*)kp;
    bf16x8 o;
#pragma unroll
    for (int p = 0; p < 4; p++) {
      float e = (float)v[2 * p], od = (float)v[2 * p + 1];
      o[2 * p] = (bf16)(e * tt[p].x - od * tt[p].y);
      o[2 * p + 1] = (bf16)(e * tt[p].y + od * tt[p].x);
    }
    *(bf16x8*)kp = o;
  }
}

// ---------------- flash attention v5: counted-vmcnt pipeline + setprio ----------------
// Q-tile 64 (4 waves x 16 q-rows), K-tile 64 dbuf, 2 blocks/CU. Counted-vmcnt
// gates (round 3, race-free): top vmcnt(4)+barrier gates K(it); PV vmcnt(8)
// +barrier gates V(it) while K/V(it+1) stay in flight.
__global__ __launch_bounds__(256, 2) void attn_k(const bf16* __restrict__ Qb, const bf16* __restrict__ Kb,
                                                 const bf16* __restrict__ Vt, bf16* __restrict__ Yb) {
  __shared__ __align__(16) bf16 Ks[2][64 * 128];
  __shared__ __align__(16) bf16 Vs[2][128 * 64];
  __shared__ __align__(16) bf16 Pl[4][16 * 76];
  int bh = blockIdx.x;
  int slot = blockIdx.y;
  int w = threadIdx.x >> 6, l = threadIdx.x & 63;
  int l15 = l & 15, quad = l >> 4;
  const bf16* Qp = Qb + (size_t)bh * SEQ * DH;
  const bf16* Kp = Kb + (size_t)bh * SEQ * DH;
  const bf16* Vp = Vt + (size_t)bh * DH * SEQ;
  int b = bh >> 4, h = bh & 15;
  f32x4 zero = {0.f, 0.f, 0.f, 0.f};
  bf16* P = &Pl[w][0];

  auto stage = [&](int it, int buf) {
    const char* gk = (const char*)Kp + (size_t)it * 16384 + w * 4096 + l * 16;
    char* lk = (char*)&Ks[buf][0] + w * 4096;
    for (int i = 0; i < 4; i++) async16(gk + i * 1024, lk + i * 1024);
    const char* gv = (const char*)Vp + (size_t)it * 128 + (size_t)(w * 32 + (l >> 3)) * (SEQ * 2) + (l & 7) * 16;
    char* lv = (char*)&Vs[buf][0] + w * 32 * 128;
    for (int i = 0; i < 4; i++) async16(gv + (size_t)i * 8 * (SEQ * 2), lv + i * 1024);
  };

  int tiles[2] = {31 - slot, slot};
  for (int half = 0; half < 2; half++) {
    int tile = tiles[half];
    int qw = tile * 64 + w * 16;  // this wave's 16 q rows
    bf16x8 qf[4];
    for (int kc = 0; kc < 4; kc++)
      qf[kc] = *(const bf16x8*)&Qp[(size_t)(qw + l15) * DH + kc * 32 + quad * 8];
    f32x4 o[8];
    for (int ns = 0; ns < 8; ns++) o[ns] = zero;
    float mprev = -1e30f, lsum = 0.f;
    int nkt = tile + 1;

    stage(0, 0);
    __syncthreads();
    for (int it = 0; it < nkt; it++) {
      int buf = it & 1;
      bool more = (it + 1 < nkt);
      // top gate: own K(it) retired (outstanding = K(it)4+V(it)4 -> 4), then
      // collective barrier: all waves' K(it) landed; buf^1 readers done.
      asm volatile("s_waitcnt vmcnt(4)" ::: "memory");
      __builtin_amdgcn_s_barrier();
      __builtin_amdgcn_sched_barrier(0);
      if (more) stage(it + 1, buf ^ 1);
      int k0 = it * 64;
      // S^T = K(row) x Q(col=l15=q)
      f32x4 st[4];
      for (int ns = 0; ns < 4; ns++) st[ns] = zero;
      __builtin_amdgcn_s_setprio(1);
      for (int kc = 0; kc < 4; kc++)
        for (int ns = 0; ns < 4; ns++) {
          bf16x8 kf = *(const bf16x8*)&Ks[buf][(ns * 16 + l15) * 128 + (((kc * 4 + quad) ^ (l15 & 7)) << 3)];
          st[ns] = mfma16(kf, qf[kc], st[ns]);
        }
      __builtin_amdgcn_s_setprio(0);
      int qq = qw + l15;
      if (k0 + 63 > qw) {  // diagonal tile: mask k > q
        for (int ns = 0; ns < 4; ns++) {
          int kk = k0 + ns * 16 + quad * 4;
          for (int r = 0; r < 4; r++)
            if (kk + r > qq) st[ns][r] = -1e30f;
        }
      }
      float pm = -1e30f;
      for (int ns = 0; ns < 4; ns++)
        for (int r = 0; r < 4; r++) pm = fmaxf(pm, st[ns][r]);
      pm = fmaxf(pm, __shfl_xor(pm, 16, 64));
      pm = fmaxf(pm, __shfl_xor(pm, 32, 64));
      float mnew = fmaxf(mprev, pm);
      float al = exp2f(mprev - mnew);
      mprev = mnew;
      float ps = 0.f;
      for (int ns = 0; ns < 4; ns++)
        for (int r = 0; r < 4; r++) {
          float e = exp2f(st[ns][r] - mnew);
          st[ns][r] = e;
          ps += e;
        }
      ps += __shfl_xor(ps, 16, 64);
      ps += __shfl_xor(ps, 32, 64);
      lsum = lsum * al + ps;
      for (int ns = 0; ns < 8; ns++) o[ns] *= al;
      // P^T (C-layout) -> P[q][k] rows: lane holds k=quad*4..+3 contiguous -> b64 writes
      for (int ns = 0; ns < 4; ns++) {
        bf16x4 pk;
        for (int r = 0; r < 4; r++) pk[r] = (bf16)st[ns][r];
        *(bf16x4*)&P[l15 * 76 + ns * 16 + quad * 4] = pk;
      }
      asm volatile("s_waitcnt lgkmcnt(0)" ::: "memory");
      bf16x8 pa[2];
      for (int kc = 0; kc < 2; kc++)
        pa[kc] = *(const bf16x8*)&P[l15 * 76 + kc * 32 + quad * 8];
      // PV gate: own V(it) retired (K/V(it+1) = 8 newer loads stay in flight),
      // then collective barrier -> all waves' V(it) landed.
      if (more) {
        asm volatile("s_waitcnt vmcnt(8)" ::: "memory");
      } else {
        asm volatile("s_waitcnt vmcnt(0)" ::: "memory");
      }
      __builtin_amdgcn_s_barrier();
      __builtin_amdgcn_sched_barrier(0);
      __builtin_amdgcn_s_setprio(1);
      for (int ns = 0; ns < 8; ns++)
        for (int kc = 0; kc < 2; kc++) {
          bf16x8 vf = *(const bf16x8*)&Vs[buf][(ns * 16 + l15) * 64 + (((kc * 4 + quad) ^ (l15 & 7)) << 3)];
          o[ns] = mfma16(vf, pa[kc], o[ns]);  // O^T: col=l15=q
        }
      __builtin_amdgcn_s_setprio(0);
    }
    __syncthreads();  // half-boundary: all reads done before next half's restage
    // epilogue: O^T col=l15=q, row(within ns)=quad*4+r -> d = ns*16+quad*4+r
    float inv = 1.0f / lsum;
    int q = qw + l15;
    size_t base = ((size_t)(b * SEQ + q)) * DIN + h * DH + quad * 4;
    for (int ns = 0; ns < 8; ns++) {
      bf16x4 pk;
      for (int r = 0; r < 4; r++) pk[r] = (bf16)(o[ns][r] * inv);
      *(bf16x4*)&Yb[base + ns * 16] = pk;
    }
  }
}

// ---------------- proj GEMM (BK=64, xor-swizzled LDS chunks) ----------------
__global__ __launch_bounds__(256) void gemm_proj_k(const bf16* __restrict__ A, const bf16* __restrict__ BT,
                                                   void* __restrict__ out, const int* __restrict__ flag) {
  __shared__ __align__(16) bf16 As[128 * 64];
  __shared__ __align__(16) bf16 Bs[128 * 64];
  const int K = DIN;
  int m0 = blockIdx.y * 128, n0 = blockIdx.x * 128;
  int tid = threadIdx.x, w = tid >> 6, l = tid & 63;
  int l15 = l & 15, quad = l >> 4;
  int wm = (w & 1) * 64, wn = (w >> 1) * 64;
  bool obf = *flag != 0;
  f32x4 zero = {0.f, 0.f, 0.f, 0.f};
  f32x4 acc[4][4];
  for (int i = 0; i < 4; i++)
    for (int j = 0; j < 4; j++) acc[i][j] = zero;
  int gch = (l & 7) ^ (l >> 3);
  const bf16* Ag = A + (size_t)(m0 + w * 32 + (l >> 3)) * K + gch * 8;
  const bf16* Bg = BT + (size_t)(n0 + w * 32 + (l >> 3)) * K + gch * 8;
  bf16* AsW = As + w * 2048;
  bf16* BsW = Bs + w * 2048;
  for (int k0 = 0; k0 < K; k0 += 64) {
    __syncthreads();
    for (int j = 0; j < 4; j++) async16(Ag + k0 + (size_t)j * 8 * K, AsW + j * 512);
    for (int j = 0; j < 4; j++) async16(Bg + k0 + (size_t)j * 8 * K, BsW + j * 512);
    __syncthreads();
    for (int kk = 0; kk < 2; kk++) {
      bf16x8 af[4], bfv[4];
      for (int i = 0; i < 4; i++)
        af[i] = *(const bf16x8*)&As[(wm + i * 16 + l15) * 64 + (((kk * 4 + quad) ^ (l15 & 7)) << 3)];
      for (int j = 0; j < 4; j++)
        bfv[j] = *(const bf16x8*)&Bs[(wn + j * 16 + l15) * 64 + (((kk * 4 + quad) ^ (l15 & 7)) << 3)];
      for (int i = 0; i < 4; i++)
        for (int j = 0; j < 4; j++) acc[i][j] = mfma16(af[i], bfv[j], acc[i][j]);
    }
  }
  for (int j = 0; j < 4; j++) {
    int col = n0 + wn + j * 16 + l15;
    for (int i = 0; i < 4; i++) {
      int mrow = m0 + wm + i * 16 + quad * 4;
      for (int r = 0; r < 4; r++) {
        size_t idx = (size_t)(mrow + r) * DIN + col;
        float v = acc[i][j][r];
        if (obf)
          ((bf16*)out)[idx] = (bf16)v;
        else
          ((float*)out)[idx] = v;
      }
    }
  }
}

extern "C" void kernel_launch(void* const* d_in, const int* in_sizes, int n_in,
                              void* d_out, int out_size, void* d_ws, size_t ws_size,
                              hipStream_t stream) {
  char* ws = (char*)d_ws;
  int* flag = (int*)ws;
  bf16* Xb = (bf16*)(ws + 256);                                  // 16 MiB, aliased with Yb
  bf16* WqkvT = (bf16*)(ws + 256 + 16777216);                    // 24 MiB
  bf16* WprojT = (bf16*)(ws + 256 + 16777216 + 25165824);        // 8 MiB
  bf16* Qb = (bf16*)(ws + 256 + 16777216 + 25165824 + 8388608);  // 16 MiB each
  bf16* Kb = Qb + (size_t)MM * DIN;
  bf16* Vb = Kb + (size_t)MM * DIN;  // V slot reused: RoPE trig LUT (1 MiB)
  bf16* Vt = Vb + (size_t)MM * DIN;
  bf16* Yb = Xb;  // Xb dead after gemm_qkv
  float2* trig = (float2*)Vb;

  sniff_k<<<1, 256, 0, stream>>>((const unsigned short*)d_in[0], flag);
  trig_k<<<512, 256, 0, stream>>>(trig);
  cast_x_k<<<4096, 256, 0, stream>>>(d_in[0], Xb, flag);
  cast_wT_k<<<dim3(192, 64), 256, 0, stream>>>(d_in[1], WqkvT, flag, DIN, N3);
  cast_wT_k<<<dim3(64, 64), 256, 0, stream>>>(d_in[2], WprojT, flag, DIN, DIN);
  gemm_qkv_k<<<dim3(48, 32), 256, 0, stream>>>(Xb, WqkvT, Qb, Kb, Vt);
  rope_lut_k<<<4096, 256, 0, stream>>>(Qb, Kb, trig);
  attn_k<<<dim3(32, 16), 256, 0, stream>>>(Qb, Kb, Vt, Yb);
  gemm_proj_k<<<dim3(16, 32), 256, 0, stream>>>(Yb, WprojT, d_out, flag);
}